// Round 1
// baseline (49.256 us; speedup 1.0000x reference)
//
#include <hip/hip_runtime.h>

#define NN 768
#define IN_DIM 128
#define WD 256      // ATTN_WIDTH
#define NH 4
#define NEG 0.01f

__device__ __forceinline__ float leaky(float x) { return fmaxf(x, NEG * x); }

// ---- K0: transpose weights into coalesced-friendly layouts ----
// preWt[k*128+d]   = preW[d*128+k]          (128x128)
// A1t[k*256+w]     = w1[w*256+k]      k<128 (dest half)
// A2t[k*256+w]     = w1[w*256+128+k]  k<128 (src half)
// postWt[k*512+c]  = postW[c*128+k]         (128x512)
__global__ void k_transpose(const float* __restrict__ preW,
                            const float* __restrict__ postW,
                            const float* __restrict__ w1,
                            float* __restrict__ preWt,
                            float* __restrict__ postWt,
                            float* __restrict__ A1t,
                            float* __restrict__ A2t) {
    int idx = blockIdx.x * blockDim.x + threadIdx.x;
    int stride = gridDim.x * blockDim.x;
    for (int t = idx; t < 128 * 128; t += stride) {
        int k = t >> 7, d = t & 127;
        preWt[t] = preW[d * 128 + k];
    }
    for (int t = idx; t < 128 * 256; t += stride) {
        int k = t >> 8, w = t & 255;
        A1t[t] = w1[w * 256 + k];
        A2t[t] = w1[w * 256 + 128 + k];
    }
    for (int t = idx; t < 128 * 512; t += stride) {
        int k = t >> 9, c = t & 511;
        postWt[t] = postW[c * 128 + k];
    }
}

// ---- K1: h_proj = nodes @ preW^T  (768x128) ----
__global__ __launch_bounds__(128) void k_hproj(const float* __restrict__ nodes,
                                               const float* __restrict__ preWt,
                                               float* __restrict__ h_proj) {
    __shared__ float row[128];
    int i = blockIdx.x, t = threadIdx.x;
    row[t] = nodes[i * 128 + t];
    __syncthreads();
    float acc = 0.f;
#pragma unroll
    for (int k = 0; k < 128; ++k)
        acc = fmaf(row[k], preWt[k * 128 + t], acc);
    h_proj[i * 128 + t] = acc;
}

// ---- K2: U = h_proj@W1a^T, Vb = h_proj@W1b^T + b1, out_h = nodes@postW^T ----
__global__ __launch_bounds__(256) void k_uv(const float* __restrict__ nodes,
                                            const float* __restrict__ h_proj,
                                            const float* __restrict__ A1t,
                                            const float* __restrict__ A2t,
                                            const float* __restrict__ postWt,
                                            const float* __restrict__ b1,
                                            float* __restrict__ U,
                                            float* __restrict__ Vb,
                                            float* __restrict__ out_h) {
    __shared__ float hrow[128];
    __shared__ float nrow[128];
    int i = blockIdx.x, t = threadIdx.x;
    if (t < 128) {
        hrow[t] = h_proj[i * 128 + t];
        nrow[t] = nodes[i * 128 + t];
    }
    __syncthreads();
    float u = 0.f, v = 0.f, o0 = 0.f, o1 = 0.f;
#pragma unroll 4
    for (int k = 0; k < 128; ++k) {
        float h = hrow[k], x = nrow[k];
        u = fmaf(h, A1t[k * 256 + t], u);
        v = fmaf(h, A2t[k * 256 + t], v);
        o0 = fmaf(x, postWt[k * 512 + t], o0);
        o1 = fmaf(x, postWt[k * 512 + t + 256], o1);
    }
    U[i * 256 + t] = u;
    Vb[i * 256 + t] = v + b1[t];
    out_h[i * 512 + t] = o0;
    out_h[i * 512 + t + 256] = o1;
}

// ---- K3: per destination row i: edge list -> scores -> masked softmax -> aggregate ----
__global__ __launch_bounds__(256) void k_attn(const float* __restrict__ adj,
                                              const float* __restrict__ U,
                                              const float* __restrict__ Vb,
                                              const float* __restrict__ out_h,
                                              const float* __restrict__ w2,
                                              const float* __restrict__ b2,
                                              float* __restrict__ out) {
    __shared__ float ulds[256];
    __shared__ float w2l[4 * 256];
    __shared__ int elist[NN];
    __shared__ float sc[NN * NH];   // scores then softmax weights, [e*4+h]
    __shared__ int ecount;

    int i = blockIdx.x, t = threadIdx.x;
    int lane = t & 63, wv = t >> 6;

    ulds[t] = U[i * 256 + t];
#pragma unroll
    for (int q = 0; q < 4; ++q) w2l[q * 256 + t] = w2[q * 256 + t];
    if (t == 0) ecount = 0;
    __syncthreads();

    // build edge list (order nondeterministic; sums are order-robust)
    for (int j = t; j < NN; j += 256) {
        if (adj[i * NN + j] != 0.0f) {
            int p = atomicAdd(&ecount, 1);
            elist[p] = j;
        }
    }
    __syncthreads();
    int ne = ecount;

    // scores: each wave takes every 4th edge
    for (int e = wv; e < ne; e += 4) {
        int j = elist[e];
        const float* vrow = Vb + j * 256;
        float a0 = 0.f, a1 = 0.f, a2 = 0.f, a3 = 0.f;
#pragma unroll
        for (int q = 0; q < 4; ++q) {
            int w = q * 64 + lane;
            float tv = leaky(ulds[w] + vrow[w]);
            a0 = fmaf(tv, w2l[w], a0);
            a1 = fmaf(tv, w2l[256 + w], a1);
            a2 = fmaf(tv, w2l[512 + w], a2);
            a3 = fmaf(tv, w2l[768 + w], a3);
        }
#pragma unroll
        for (int off = 32; off; off >>= 1) {
            a0 += __shfl_xor(a0, off);
            a1 += __shfl_xor(a1, off);
            a2 += __shfl_xor(a2, off);
            a3 += __shfl_xor(a3, off);
        }
        if (lane == 0) {
            sc[e * 4 + 0] = leaky(a0 + b2[0]);
            sc[e * 4 + 1] = leaky(a1 + b2[1]);
            sc[e * 4 + 2] = leaky(a2 + b2[2]);
            sc[e * 4 + 3] = leaky(a3 + b2[3]);
        }
    }
    __syncthreads();

    // masked softmax over edges, one wave per head
    {
        int h = wv;  // 4 waves, 4 heads
        float m = -INFINITY;
        for (int e = lane; e < ne; e += 64) m = fmaxf(m, sc[e * 4 + h]);
#pragma unroll
        for (int off = 32; off; off >>= 1) m = fmaxf(m, __shfl_xor(m, off));
        float s = 0.f;
        for (int e = lane; e < ne; e += 64) {
            float p = expf(sc[e * 4 + h] - m);
            sc[e * 4 + h] = p;
            s += p;
        }
#pragma unroll
        for (int off = 32; off; off >>= 1) s += __shfl_xor(s, off);
        float inv = 1.0f / s;
        for (int e = lane; e < ne; e += 64) sc[e * 4 + h] *= inv;
    }
    __syncthreads();

    // aggregate: out[i, c] = sum_e w[e, c&3] * out_h[j_e, c], c = t and t+256
    float acc0 = 0.f, acc1 = 0.f;
    int h = t & 3;
    for (int e = 0; e < ne; ++e) {
        int j = elist[e];
        float wgt = sc[e * 4 + h];
        acc0 = fmaf(wgt, out_h[j * 512 + t], acc0);
        acc1 = fmaf(wgt, out_h[j * 512 + 256 + t], acc1);
    }
    out[i * 512 + t] = acc0;
    out[i * 512 + 256 + t] = acc1;
}

extern "C" void kernel_launch(void* const* d_in, const int* in_sizes, int n_in,
                              void* d_out, int out_size, void* d_ws, size_t ws_size,
                              hipStream_t stream) {
    const float* nodes = (const float*)d_in[0];
    const float* adj   = (const float*)d_in[1];
    const float* preW  = (const float*)d_in[2];
    const float* postW = (const float*)d_in[3];
    const float* w1    = (const float*)d_in[4];
    const float* b1    = (const float*)d_in[5];
    const float* w2    = (const float*)d_in[6];
    const float* b2    = (const float*)d_in[7];
    float* out = (float*)d_out;

    float* ws = (float*)d_ws;
    float* preWt  = ws;                  // 16384
    float* A1t    = preWt + 16384;       // 32768
    float* A2t    = A1t + 32768;         // 32768
    float* postWt = A2t + 32768;         // 65536
    float* h_proj = postWt + 65536;      // 98304
    float* U      = h_proj + 98304;      // 196608
    float* Vb     = U + 196608;          // 196608
    float* out_h  = Vb + 196608;         // 393216
    // total: 1,032,192 floats ≈ 4.1 MB

    k_transpose<<<dim3(256), dim3(256), 0, stream>>>(preW, postW, w1, preWt, postWt, A1t, A2t);
    k_hproj<<<dim3(NN), dim3(128), 0, stream>>>(nodes, preWt, h_proj);
    k_uv<<<dim3(NN), dim3(256), 0, stream>>>(nodes, h_proj, A1t, A2t, postWt, b1, U, Vb, out_h);
    k_attn<<<dim3(NN), dim3(256), 0, stream>>>(adj, U, Vb, out_h, w2, b2, out);
}